// Round 5
// baseline (195.435 us; speedup 1.0000x reference)
//
#include <hip/hip_runtime.h>
#include <cfloat>

// Problem constants: M=N=64 grid, DIM=512, B=4096, SIGMA=32
#define DIMK 512
#define MN   4096
#define BATCH 4096
#define BK 32
#define NCHUNK 64   // per-row argmin partials: 64 chunks of 64 cols

typedef _Float16 half8_t __attribute__((ext_vector_type(8)));
typedef float f32x4 __attribute__((ext_vector_type(4)));

// ---------------------------------------------------------------------------
// Fused score kernel: s[b,k] = w2[k] - 2*dot(X[b],W[k]) with full-fp32-grade
// accuracy via 3-product f16 hi/mid split, computed from the ORIGINAL fp32
// arrays (no pre-convert pass):
//   - A (X) tiles: fp32 global -> in-register split -> f16 LDS (double-
//     buffered 2x16KB, ONE barrier per K-iter; prefetch issued a full MFMA
//     phase before its consuming barrier).
//   - B (W) fragments: fp32 global -> VGPR direct (no LDS, no barrier
//     coupling), split in-register; w2 accumulated from the same fp32 values
//     (exact) and quad-reduced at the end.
//   - per-(row, 64-col chunk) argmin partials to workspace.
// grid (32,32), 256 threads; wave w: m-half wm=w>>1, n-half wn=w&1, 64x64
// region = 4x4 MFMA tiles of 16x16x32.
// ---------------------------------------------------------------------------
__global__ __launch_bounds__(256, 2) void score_kernel(
        const float* __restrict__ X, const float* __restrict__ W,
        float* __restrict__ pval, int* __restrict__ pidx) {
    // A dbuf: each buf = hi[4096] | mid[4096] f16 (16 KB); 32 KB total
    __shared__ __align__(16) _Float16 lds[2][8192];

    const int t    = threadIdx.x;
    const int lane = t & 63;
    const int w    = t >> 6;
    const int wm   = w >> 1;
    const int wn   = w & 1;
    const int m0   = blockIdx.y * 128;
    const int n0   = blockIdx.x * 128;
    const int r16  = lane & 15;
    const int oct  = lane >> 4;     // k-octet 0..3

    f32x4 acc[4][4];
#pragma unroll
    for (int i = 0; i < 4; i++)
#pragma unroll
        for (int j = 0; j < 4; j++) acc[i][j] = (f32x4){0.f, 0.f, 0.f, 0.f};
    float w2a[4] = {0.f, 0.f, 0.f, 0.f};

    // A staging: wave w owns 16-row groups (2w, 2w+1). Lane l loads global
    // row (group*16 + l&15), k-span oct*8..+8 (8 fp32), deposits 8 f16 hi and
    // 8 f16 mid at lane*16B within the group's 1KB LDS block — exactly the
    // MFMA A-fragment layout (row=l&15, k=oct*8+e).
    const float* gA0 = X + (size_t)(m0 + (2 * w + 0) * 16 + r16) * DIMK + oct * 8;
    const float* gA1 = X + (size_t)(m0 + (2 * w + 1) * 16 + r16) * DIMK + oct * 8;
    const int dp0 = (2 * w + 0) * 512 + lane * 8;   // f16 offset in buf
    const int dp1 = (2 * w + 1) * 512 + lane * 8;

    // B pointers per n-tile j (16 cols each)
    const float* gB[4];
#pragma unroll
    for (int j = 0; j < 4; j++)
        gB[j] = W + (size_t)(n0 + wn * 64 + j * 16 + r16) * DIMK + oct * 8;

    // ---- prologue: stage A(k=0) into buf 0 ----
    {
        float4 a0 = *(const float4*)(gA0);
        float4 a0b = *(const float4*)(gA0 + 4);
        float4 a1 = *(const float4*)(gA1);
        float4 a1b = *(const float4*)(gA1 + 4);
        float v0[8] = {a0.x, a0.y, a0.z, a0.w, a0b.x, a0b.y, a0b.z, a0b.w};
        float v1[8] = {a1.x, a1.y, a1.z, a1.w, a1b.x, a1b.y, a1b.z, a1b.w};
        half8_t h0, m0v, h1, m1v;
#pragma unroll
        for (int e = 0; e < 8; e++) {
            _Float16 h = (_Float16)v0[e];
            h0[e] = h; m0v[e] = (_Float16)(v0[e] - (float)h);
            _Float16 g = (_Float16)v1[e];
            h1[e] = g; m1v[e] = (_Float16)(v1[e] - (float)g);
        }
        *(half8_t*)&lds[0][dp0] = h0;
        *(half8_t*)&lds[0][4096 + dp0] = m0v;
        *(half8_t*)&lds[0][dp1] = h1;
        *(half8_t*)&lds[0][4096 + dp1] = m1v;
    }
    __syncthreads();

    int cur = 0;
    for (int k0 = 0; k0 < DIMK; k0 += BK) {
        const bool more = (k0 + BK) < DIMK;
        // --- issue A(k+1) global loads first (longest latency distance) ---
        float4 na0, na0b, na1, na1b;
        if (more) {
            na0  = *(const float4*)(gA0 + k0 + BK);
            na0b = *(const float4*)(gA0 + k0 + BK + 4);
            na1  = *(const float4*)(gA1 + k0 + BK);
            na1b = *(const float4*)(gA1 + k0 + BK + 4);
        }
        // --- B(k) fp32 loads + in-register split + w2 accumulation ---
        half8_t bh[4], bm[4];
#pragma unroll
        for (int j = 0; j < 4; j++) {
            float4 b0 = *(const float4*)(gB[j] + k0);
            float4 b1 = *(const float4*)(gB[j] + k0 + 4);
            float bv[8] = {b0.x, b0.y, b0.z, b0.w, b1.x, b1.y, b1.z, b1.w};
            float s2 = 0.f;
            half8_t hh, mm;
#pragma unroll
            for (int e = 0; e < 8; e++) {
                float v = bv[e];
                s2 += v * v;
                _Float16 h = (_Float16)v;
                hh[e] = h;
                mm[e] = (_Float16)(v - (float)h);
            }
            w2a[j] += s2;
            bh[j] = hh; bm[j] = mm;
        }
        // --- A(k) fragments from LDS ---
        half8_t ah[4], am[4];
#pragma unroll
        for (int i = 0; i < 4; i++) {
            ah[i] = *(const half8_t*)&lds[cur][(wm * 4 + i) * 512 + lane * 8];
            am[i] = *(const half8_t*)&lds[cur][4096 + (wm * 4 + i) * 512 + lane * 8];
        }
        // --- 48 MFMA ---
#pragma unroll
        for (int i = 0; i < 4; i++)
#pragma unroll
            for (int j = 0; j < 4; j++) {
                acc[i][j] = __builtin_amdgcn_mfma_f32_16x16x32_f16(am[i], bh[j], acc[i][j], 0, 0, 0);
                acc[i][j] = __builtin_amdgcn_mfma_f32_16x16x32_f16(ah[i], bm[j], acc[i][j], 0, 0, 0);
                acc[i][j] = __builtin_amdgcn_mfma_f32_16x16x32_f16(ah[i], bh[j], acc[i][j], 0, 0, 0);
            }
        // --- convert + deposit A(k+1) into alternate buffer ---
        if (more) {
            float v0[8] = {na0.x, na0.y, na0.z, na0.w, na0b.x, na0b.y, na0b.z, na0b.w};
            float v1[8] = {na1.x, na1.y, na1.z, na1.w, na1b.x, na1b.y, na1b.z, na1b.w};
            half8_t h0, m0v, h1, m1v;
#pragma unroll
            for (int e = 0; e < 8; e++) {
                _Float16 h = (_Float16)v0[e];
                h0[e] = h; m0v[e] = (_Float16)(v0[e] - (float)h);
                _Float16 g = (_Float16)v1[e];
                h1[e] = g; m1v[e] = (_Float16)(v1[e] - (float)g);
            }
            _Float16* nb = &lds[cur ^ 1][0];
            *(half8_t*)&nb[dp0] = h0;
            *(half8_t*)&nb[4096 + dp0] = m0v;
            *(half8_t*)&nb[dp1] = h1;
            *(half8_t*)&nb[4096 + dp1] = m1v;
        }
        cur ^= 1;
        __syncthreads();   // next buf deposited; everyone done reading old buf
    }

    // ---- w2: reduce k-octet partials across quads (cols = lane&15) ----
#pragma unroll
    for (int j = 0; j < 4; j++) {
        w2a[j] += __shfl_xor(w2a[j], 16);
        w2a[j] += __shfl_xor(w2a[j], 32);
    }

    // ---- per-row argmin over this wave's 64 cols ----
    // D layout: col = lane&15, row = (lane>>4)*4 + v   (m89/m91 verified)
    int ncol[4];
#pragma unroll
    for (int j = 0; j < 4; j++) ncol[j] = n0 + wn * 64 + j * 16 + r16;
#pragma unroll
    for (int i = 0; i < 4; i++)
#pragma unroll
        for (int v = 0; v < 4; v++) {
            float bv = FLT_MAX;
            int   bi = 0x7FFFFFFF;
#pragma unroll
            for (int j = 0; j < 4; j++) {        // j ascending -> ties keep lower n
                float s = w2a[j] - 2.0f * acc[i][j][v];
                if (s < bv) { bv = s; bi = ncol[j]; }
            }
#pragma unroll
            for (int mask = 1; mask <= 8; mask <<= 1) {   // reduce over 16 col-lanes
                float ov = __shfl_xor(bv, mask);
                int   oi = __shfl_xor(bi, mask);
                if (ov < bv || (ov == bv && oi < bi)) { bv = ov; bi = oi; }
            }
            if (r16 == 0) {
                int m = m0 + wm * 64 + i * 16 + oct * 4 + v;
                int chunk = blockIdx.x * 2 + wn;
                pval[(size_t)m * NCHUNK + chunk] = bv;
                pidx[(size_t)m * NCHUNK + chunk] = bi;
            }
        }
}

// ---------------------------------------------------------------------------
// Final: reduce 64 partials/row -> BMU, separable Gaussian, write 4096 floats.
// ---------------------------------------------------------------------------
__global__ __launch_bounds__(256) void epilogue_kernel(
        const float* __restrict__ pval, const int* __restrict__ pidx,
        const int* __restrict__ decay_p, const int* __restrict__ it_p,
        float* __restrict__ out) {
    __shared__ float er[64];
    __shared__ float ec[64];
    __shared__ int   s_idx;
    const int b = blockIdx.x;
    const int t = threadIdx.x;

    if (t < 64) {
        float v  = pval[(size_t)b * NCHUNK + t];
        int   ii = pidx[(size_t)b * NCHUNK + t];
#pragma unroll
        for (int mask = 1; mask <= 32; mask <<= 1) {
            float ov = __shfl_xor(v, mask);
            int   oi = __shfl_xor(ii, mask);
            if (ov < v || (ov == v && oi < ii)) { v = ov; ii = oi; }
        }
        if (t == 0) s_idx = ii;
    }
    __syncthreads();
    const int r = s_idx >> 6;
    const int c = s_idx & 63;
    const float lr  = expf(-(float)(*it_p) / (float)(*decay_p));
    const float so  = 32.0f * lr;          // SIGMA = 32
    const float inv = 1.0f / (so * so);
    if (t < 64) {
        float d = (float)(t - r);
        er[t] = expf(-d * d * inv);
    } else if (t < 128) {
        int j = t - 64;
        float d = (float)(j - c);
        ec[j] = expf(-d * d * inv);
    }
    __syncthreads();
    float4* out4 = (float4*)(out + (size_t)b * 4096);
#pragma unroll
    for (int qq = 0; qq < 4; qq++) {
        int f  = t + 256 * qq;
        int i  = f >> 4;
        int j0 = (f & 15) * 4;
        float e = er[i];
        out4[f] = make_float4(e * ec[j0], e * ec[j0 + 1],
                              e * ec[j0 + 2], e * ec[j0 + 3]);
    }
}

// ---------------------------------------------------------------------------
extern "C" void kernel_launch(void* const* d_in, const int* in_sizes, int n_in,
                              void* d_out, int out_size, void* d_ws, size_t ws_size,
                              hipStream_t stream) {
    const float* X       = (const float*)d_in[0];   // [4096,512]
    const float* W       = (const float*)d_in[1];   // [4096,512]
    const int*   decay_p = (const int*)d_in[3];
    const int*   it_p    = (const int*)d_in[4];
    float* out = (float*)d_out;

    // ws: pval 1MB | pidx 1MB
    float* pval = (float*)d_ws;
    int*   pidx = (int*)(pval + (size_t)BATCH * NCHUNK);

    score_kernel<<<dim3(32, 32), 256, 0, stream>>>(X, W, pval, pidx);
    epilogue_kernel<<<BATCH, 256, 0, stream>>>(pval, pidx, decay_p, it_p, out);
}